// Round 6
// baseline (220.734 us; speedup 1.0000x reference)
//
#include <hip/hip_runtime.h>

// LDDMM variational evolve: B=1, N=8192, D=3, fp32.
// dmom_i = 2g * (x_i * sum_j w_ij  -  sum_j w_ij x_j),  w_ij = K_ij <p_i,p_j>
// dx_i   = sum_j K_ij p_j,   K_ij = exp(-g |x_i - x_j|^2), g = 100.
//
// Round 9: r5 diagnostic (repeat=2) finally exposed partial's counters:
// VALUBusy 68%, zero LDS conflicts, HBM 6% -> ~92% issue-port saturated once
// v_exp_f32 is calibrated at ~18-20 cyc/wave64. Explains r2/r3/r4 neutrality
// (ILP/occupancy/v_pk all leave issue cycles unchanged; pk fp32 is half-rate
// per instr on CDNA4). This round cuts issue cycles + covers residual stall:
//   - drop `a += w` (a_i = p_i . g_i, derived in finalize from reduced G);
//     part shrinks 7 -> 6 channels (25.4 MB, reduce -0.7us).
//   - TPB 512 for partial: 4 blocks/CU x 8 waves = 32 waves/CU (was 16),
//     __launch_bounds__(512,8); VGPR was 40 so no spill at the 64 cap.
// NOTE: ci must stay inside the exponent (arg <= 0 always); factoring
// exp2(ci) out overflows: inner arg reaches +432 -> inf * 0 = NaN.

#define TPB 256    // reduce / finalize / fallback
#define TPBP 512   // partial
#define ITILE 2
constexpr float GAMMA_C = 100.0f;
constexpr float LOG2E_C = 1.4426950408889634f;
constexpr float SB_C    = 2.0f * GAMMA_C * LOG2E_C;  // A.xyz = SB*x_j
constexpr float SC_C    = -GAMMA_C * LOG2E_C;        // A.w   = SC*|x_j|^2
constexpr float LN2_C   = 0.69314718055994531f;      // 2g/SB

// ---- Kernel A: per-segment partial sums ------------------------------------
// grid (N/(TPBP*ITILE), SEG). part layout: P[c][s][i], c=0..5 (wx,wy,wz,gx,gy,gz).
__global__ __launch_bounds__(TPBP, 8) void lddmm_partial(
    const float* __restrict__ mom, const float* __restrict__ xpt,
    float* __restrict__ part, int N, int SEG, int JT) {
  extern __shared__ float4 smem[];
  float4* sA = smem;        // {SB*x, SB*y, SB*z, SC*|x|^2}
  float4* sP = smem + JT;   // {px, py, pz, 0}
  const int tid = threadIdx.x;
  const int seg = blockIdx.y;

  for (int t = tid; t < JT; t += TPBP) {
    const int j = seg * JT + t;
    const float bx = xpt[3*j], by = xpt[3*j+1], bz = xpt[3*j+2];
    sA[t] = make_float4(SB_C*bx, SB_C*by, SB_C*bz,
                        SC_C * fmaf(bx, bx, fmaf(by, by, bz*bz)));
    sP[t] = make_float4(mom[3*j], mom[3*j+1], mom[3*j+2], 0.f);
  }
  __syncthreads();

  const int i0 = blockIdx.x * (TPBP * ITILE) + tid;
  const int i1 = i0 + TPBP;

  const float x0 = xpt[3*i0], y0 = xpt[3*i0+1], z0 = xpt[3*i0+2];
  const float p0x = mom[3*i0], p0y = mom[3*i0+1], p0z = mom[3*i0+2];
  const float c0 = SC_C * fmaf(x0, x0, fmaf(y0, y0, z0*z0));
  const float x1 = xpt[3*i1], y1 = xpt[3*i1+1], z1 = xpt[3*i1+2];
  const float p1x = mom[3*i1], p1y = mom[3*i1+1], p1z = mom[3*i1+2];
  const float c1 = SC_C * fmaf(x1, x1, fmaf(y1, y1, z1*z1));

  float wx0=0.f, wy0=0.f, wz0=0.f, gx0=0.f, gy0=0.f, gz0=0.f;
  float wx1=0.f, wy1=0.f, wz1=0.f, gx1=0.f, gy1=0.f, gz1=0.f;

#pragma unroll 4
  for (int t = 0; t < JT; ++t) {
    const float4 A = sA[t];   // broadcast (same addr all lanes): conflict-free
    const float4 P = sP[t];
    // i0  (14 VALU + 1 exp; no row-sum accumulation)
    {
      const float arg = fmaf(A.x, x0, fmaf(A.y, y0, fmaf(A.z, z0, c0 + A.w)));
      const float K   = __builtin_amdgcn_exp2f(arg);          // bare v_exp_f32
      const float dot = fmaf(P.x, p0x, fmaf(P.y, p0y, P.z * p0z));
      const float w   = K * dot;
      wx0 = fmaf(w, A.x, wx0); wy0 = fmaf(w, A.y, wy0); wz0 = fmaf(w, A.z, wz0);
      gx0 = fmaf(K, P.x, gx0); gy0 = fmaf(K, P.y, gy0); gz0 = fmaf(K, P.z, gz0);
    }
    // i1
    {
      const float arg = fmaf(A.x, x1, fmaf(A.y, y1, fmaf(A.z, z1, c1 + A.w)));
      const float K   = __builtin_amdgcn_exp2f(arg);
      const float dot = fmaf(P.x, p1x, fmaf(P.y, p1y, P.z * p1z));
      const float w   = K * dot;
      wx1 = fmaf(w, A.x, wx1); wy1 = fmaf(w, A.y, wy1); wz1 = fmaf(w, A.z, wz1);
      gx1 = fmaf(K, P.x, gx1); gy1 = fmaf(K, P.y, gy1); gz1 = fmaf(K, P.z, gz1);
    }
  }

  const size_t SN = (size_t)SEG * N;
  float* p = part + (size_t)seg * N;
  p[0*SN+i0] = wx0; p[0*SN+i1] = wx1;
  p[1*SN+i0] = wy0; p[1*SN+i1] = wy1;
  p[2*SN+i0] = wz0; p[2*SN+i1] = wz1;
  p[3*SN+i0] = gx0; p[3*SN+i1] = gx1;
  p[4*SN+i0] = gy0; p[4*SN+i1] = gy1;
  p[5*SN+i0] = gz0; p[5*SN+i1] = gz1;
}

// ---- Kernel B: reduce over segments (parallel over channels) ---------------
__global__ __launch_bounds__(TPB) void lddmm_reduce(
    const float* __restrict__ part, float* __restrict__ R, int N, int SEG) {
  const int i = blockIdx.x * TPB + threadIdx.x;
  const int c = blockIdx.y;
  const float* src = part + (size_t)c * SEG * N + i;
  float s0 = 0.f, s1 = 0.f, s2 = 0.f, s3 = 0.f;
  int s = 0;
  for (; s + 4 <= SEG; s += 4) {
    s0 += src[(size_t)(s+0)*N]; s1 += src[(size_t)(s+1)*N];
    s2 += src[(size_t)(s+2)*N]; s3 += src[(size_t)(s+3)*N];
  }
  for (; s < SEG; ++s) s0 += src[(size_t)s*N];
  R[(size_t)c * N + i] = (s0 + s1) + (s2 + s3);
}

// ---- Kernel C: finalize ----------------------------------------------------
// A_i = p_i . G_i (row-sum of W, recovered from the reduced G channels).
__global__ __launch_bounds__(TPB) void lddmm_finalize(
    const float* __restrict__ R, const float* __restrict__ xpt,
    const float* __restrict__ mom, float* __restrict__ out, int N) {
  const int i = blockIdx.x * TPB + threadIdx.x;
  const float WX = R[(size_t)0*N+i], WY = R[(size_t)1*N+i], WZ = R[(size_t)2*N+i];
  const float GX = R[(size_t)3*N+i], GY = R[(size_t)4*N+i], GZ = R[(size_t)5*N+i];
  const float xi = xpt[3*i], yi = xpt[3*i+1], zi = xpt[3*i+2];
  const float px = mom[3*i], py = mom[3*i+1], pz = mom[3*i+2];
  const float A  = fmaf(px, GX, fmaf(py, GY, pz * GZ));
  const float TGA = 2.0f * GAMMA_C * A;
  out[3*i+0] = fmaf(TGA, xi, -LN2_C * WX);
  out[3*i+1] = fmaf(TGA, yi, -LN2_C * WY);
  out[3*i+2] = fmaf(TGA, zi, -LN2_C * WZ);
  out[3*N + 3*i + 0] = GX;
  out[3*N + 3*i + 1] = GY;
  out[3*N + 3*i + 2] = GZ;
}

// ---- Fallback (tiny ws): atomic single-kernel version ----------------------
__global__ __launch_bounds__(TPB) void lddmm_atomic(
    const float* __restrict__ mom, const float* __restrict__ xpt,
    float* __restrict__ out, int N) {
  const int i  = blockIdx.x * TPB + threadIdx.x;
  const int jb = blockIdx.y * TPB;
  __shared__ float4 sA[TPB], sP[TPB];
  {
    const int j = jb + threadIdx.x;
    const float bx = xpt[3*j], by = xpt[3*j+1], bz = xpt[3*j+2];
    sA[threadIdx.x] = make_float4(SB_C*bx, SB_C*by, SB_C*bz,
                                  SC_C * fmaf(bx, bx, fmaf(by, by, bz*bz)));
    sP[threadIdx.x] = make_float4(mom[3*j], mom[3*j+1], mom[3*j+2], 0.f);
  }
  __syncthreads();
  const float xi = xpt[3*i], yi = xpt[3*i+1], zi = xpt[3*i+2];
  const float pxi = mom[3*i], pyi = mom[3*i+1], pzi = mom[3*i+2];
  const float ci = SC_C * fmaf(xi, xi, fmaf(yi, yi, zi*zi));
  float a=0.f, wx=0.f, wy=0.f, wz=0.f, gx=0.f, gy=0.f, gz=0.f;
#pragma unroll 4
  for (int t = 0; t < TPB; ++t) {
    const float4 A = sA[t], P = sP[t];
    const float arg = fmaf(A.x, xi, fmaf(A.y, yi, fmaf(A.z, zi, ci + A.w)));
    const float K   = __builtin_amdgcn_exp2f(arg);
    const float dot = fmaf(P.x, pxi, fmaf(P.y, pyi, P.z * pzi));
    const float w   = K * dot;
    a += w;
    wx = fmaf(w, A.x, wx); wy = fmaf(w, A.y, wy); wz = fmaf(w, A.z, wz);
    gx = fmaf(K, P.x, gx); gy = fmaf(K, P.y, gy); gz = fmaf(K, P.z, gz);
  }
  const float TGA = 2.0f * GAMMA_C * a;
  atomicAdd(&out[3*i+0], fmaf(TGA, xi, -LN2_C * wx));
  atomicAdd(&out[3*i+1], fmaf(TGA, yi, -LN2_C * wy));
  atomicAdd(&out[3*i+2], fmaf(TGA, zi, -LN2_C * wz));
  atomicAdd(&out[3*N+3*i+0], gx);
  atomicAdd(&out[3*N+3*i+1], gy);
  atomicAdd(&out[3*N+3*i+2], gz);
}

extern "C" void kernel_launch(void* const* d_in, const int* in_sizes, int n_in,
                              void* d_out, int out_size, void* d_ws, size_t ws_size,
                              hipStream_t stream) {
  const float* mom = (const float*)d_in[0];   // setup_inputs order: mom first
  const float* xpt = (const float*)d_in[1];   // control_points second
  float* out = (float*)d_out;
  const int N = in_sizes[0] / 3;              // 8192

  // ws layout: part (6*SEG*N floats) | R (6*N floats)
  auto need = [&](int s) { return (size_t)(6*s + 6) * (size_t)N * sizeof(float); };
  int SEG = 128;
  while (SEG > 2 && need(SEG) > ws_size) SEG >>= 1;

  const bool shapes_ok = (N % (TPBP * ITILE) == 0) && (N % SEG == 0) &&
                         (N % TPB == 0);
  if (need(SEG) <= ws_size && shapes_ok) {
    const int JT = N / SEG;                   // 64 @ SEG=128
    float* partb = (float*)d_ws;
    float* R     = partb + (size_t)6 * SEG * N;
    const size_t shmem = (size_t)JT * 2 * sizeof(float4);   // 2 KB @ JT=64
    dim3 gA(N / (TPBP * ITILE), SEG);         // (8, 128) = 1024 blocks, 4/CU
    lddmm_partial<<<gA, TPBP, shmem, stream>>>(mom, xpt, partb, N, SEG, JT);
    dim3 gB(N / TPB, 6);                      // 192 blocks — parallel reduce
    lddmm_reduce<<<gB, TPB, 0, stream>>>(partb, R, N, SEG);
    lddmm_finalize<<<N / TPB, TPB, 0, stream>>>(R, xpt, mom, out, N);
  } else {
    hipMemsetAsync(d_out, 0, (size_t)out_size * sizeof(float), stream);
    dim3 grid(N / TPB, N / TPB);
    lddmm_atomic<<<grid, TPB, 0, stream>>>(mom, xpt, out, N);
  }
}

// Round 7
// 101.923 us; speedup vs baseline: 2.1657x; 2.1657x over previous
//
#include <hip/hip_runtime.h>

// LDDMM variational evolve: B=1, N=8192, D=3, fp32.
// dmom_i = 2g * (x_i * sum_j w_ij  -  sum_j w_ij x_j),  w_ij = K_ij <p_i,p_j>
// dx_i   = sum_j K_ij p_j,   K_ij = exp(-g |x_i - x_j|^2), g = 100.
//
// Round 10: r6's __launch_bounds__(512,8) forced VGPR 40->32 and spilled the
// j-loop to scratch (WRITE_SIZE 255MB vs 25MB logical, VALUBusy 68->18%,
// partial 40->160us). Reverted to the proven allocation: TPB=256,
// __launch_bounds__(256,4), VGPR=40, zero spill. Kept from r6 (correct, and
// -1 VALU/pair): 6-channel partials with A_i = p_i . G_i in finalize.
// New: SEG=128 with ITILE=2 -> grid (16,128) = 2048 blocks = 8 blocks/CU =
// 32 waves/CU co-resident (vs 16 before) to cover the ~32% issue stall that
// r5's diagnostic exposed (VALUBusy 68%, issue model ~46cyc/pair: 28 VALU +
// ~18 exp). Occupancy may exceed the lb hint; 40 VGPR allows 12 waves/SIMD.
// NOTE: ci must stay inside the exponent (arg <= 0 always); factoring
// exp2(ci) out overflows: inner arg reaches +432 -> inf * 0 = NaN.

#define TPB 256
#define ITILE 2
constexpr float GAMMA_C = 100.0f;
constexpr float LOG2E_C = 1.4426950408889634f;
constexpr float SB_C    = 2.0f * GAMMA_C * LOG2E_C;  // A.xyz = SB*x_j
constexpr float SC_C    = -GAMMA_C * LOG2E_C;        // A.w   = SC*|x_j|^2
constexpr float LN2_C   = 0.69314718055994531f;      // 2g/SB

// ---- Kernel A: per-segment partial sums ------------------------------------
// grid (N/(TPB*ITILE), SEG). part layout: P[c][s][i], c=0..5 (wx,wy,wz,gx,gy,gz).
__global__ __launch_bounds__(TPB, 4) void lddmm_partial(
    const float* __restrict__ mom, const float* __restrict__ xpt,
    float* __restrict__ part, int N, int SEG, int JT) {
  extern __shared__ float4 smem[];
  float4* sA = smem;        // {SB*x, SB*y, SB*z, SC*|x|^2}
  float4* sP = smem + JT;   // {px, py, pz, 0}
  const int tid = threadIdx.x;
  const int seg = blockIdx.y;

  for (int t = tid; t < JT; t += TPB) {
    const int j = seg * JT + t;
    const float bx = xpt[3*j], by = xpt[3*j+1], bz = xpt[3*j+2];
    sA[t] = make_float4(SB_C*bx, SB_C*by, SB_C*bz,
                        SC_C * fmaf(bx, bx, fmaf(by, by, bz*bz)));
    sP[t] = make_float4(mom[3*j], mom[3*j+1], mom[3*j+2], 0.f);
  }
  __syncthreads();

  const int i0 = blockIdx.x * (TPB * ITILE) + tid;
  const int i1 = i0 + TPB;

  const float x0 = xpt[3*i0], y0 = xpt[3*i0+1], z0 = xpt[3*i0+2];
  const float p0x = mom[3*i0], p0y = mom[3*i0+1], p0z = mom[3*i0+2];
  const float c0 = SC_C * fmaf(x0, x0, fmaf(y0, y0, z0*z0));
  const float x1 = xpt[3*i1], y1 = xpt[3*i1+1], z1 = xpt[3*i1+2];
  const float p1x = mom[3*i1], p1y = mom[3*i1+1], p1z = mom[3*i1+2];
  const float c1 = SC_C * fmaf(x1, x1, fmaf(y1, y1, z1*z1));

  float wx0=0.f, wy0=0.f, wz0=0.f, gx0=0.f, gy0=0.f, gz0=0.f;
  float wx1=0.f, wy1=0.f, wz1=0.f, gx1=0.f, gy1=0.f, gz1=0.f;

#pragma unroll 4
  for (int t = 0; t < JT; ++t) {
    const float4 A = sA[t];   // broadcast (same addr all lanes): conflict-free
    const float4 P = sP[t];
    // i0  (14 VALU + 1 exp; row-sum dropped, A_i recovered as p_i.G_i)
    {
      const float arg = fmaf(A.x, x0, fmaf(A.y, y0, fmaf(A.z, z0, c0 + A.w)));
      const float K   = __builtin_amdgcn_exp2f(arg);          // bare v_exp_f32
      const float dot = fmaf(P.x, p0x, fmaf(P.y, p0y, P.z * p0z));
      const float w   = K * dot;
      wx0 = fmaf(w, A.x, wx0); wy0 = fmaf(w, A.y, wy0); wz0 = fmaf(w, A.z, wz0);
      gx0 = fmaf(K, P.x, gx0); gy0 = fmaf(K, P.y, gy0); gz0 = fmaf(K, P.z, gz0);
    }
    // i1
    {
      const float arg = fmaf(A.x, x1, fmaf(A.y, y1, fmaf(A.z, z1, c1 + A.w)));
      const float K   = __builtin_amdgcn_exp2f(arg);
      const float dot = fmaf(P.x, p1x, fmaf(P.y, p1y, P.z * p1z));
      const float w   = K * dot;
      wx1 = fmaf(w, A.x, wx1); wy1 = fmaf(w, A.y, wy1); wz1 = fmaf(w, A.z, wz1);
      gx1 = fmaf(K, P.x, gx1); gy1 = fmaf(K, P.y, gy1); gz1 = fmaf(K, P.z, gz1);
    }
  }

  const size_t SN = (size_t)SEG * N;
  float* p = part + (size_t)seg * N;
  p[0*SN+i0] = wx0; p[0*SN+i1] = wx1;
  p[1*SN+i0] = wy0; p[1*SN+i1] = wy1;
  p[2*SN+i0] = wz0; p[2*SN+i1] = wz1;
  p[3*SN+i0] = gx0; p[3*SN+i1] = gx1;
  p[4*SN+i0] = gy0; p[4*SN+i1] = gy1;
  p[5*SN+i0] = gz0; p[5*SN+i1] = gz1;
}

// ---- Kernel B: reduce over segments (parallel over channels) ---------------
__global__ __launch_bounds__(TPB) void lddmm_reduce(
    const float* __restrict__ part, float* __restrict__ R, int N, int SEG) {
  const int i = blockIdx.x * TPB + threadIdx.x;
  const int c = blockIdx.y;
  const float* src = part + (size_t)c * SEG * N + i;
  float s0 = 0.f, s1 = 0.f, s2 = 0.f, s3 = 0.f;
  int s = 0;
  for (; s + 4 <= SEG; s += 4) {
    s0 += src[(size_t)(s+0)*N]; s1 += src[(size_t)(s+1)*N];
    s2 += src[(size_t)(s+2)*N]; s3 += src[(size_t)(s+3)*N];
  }
  for (; s < SEG; ++s) s0 += src[(size_t)s*N];
  R[(size_t)c * N + i] = (s0 + s1) + (s2 + s3);
}

// ---- Kernel C: finalize ----------------------------------------------------
// A_i = p_i . G_i (row-sum of W, recovered from the reduced G channels).
__global__ __launch_bounds__(TPB) void lddmm_finalize(
    const float* __restrict__ R, const float* __restrict__ xpt,
    const float* __restrict__ mom, float* __restrict__ out, int N) {
  const int i = blockIdx.x * TPB + threadIdx.x;
  const float WX = R[(size_t)0*N+i], WY = R[(size_t)1*N+i], WZ = R[(size_t)2*N+i];
  const float GX = R[(size_t)3*N+i], GY = R[(size_t)4*N+i], GZ = R[(size_t)5*N+i];
  const float xi = xpt[3*i], yi = xpt[3*i+1], zi = xpt[3*i+2];
  const float px = mom[3*i], py = mom[3*i+1], pz = mom[3*i+2];
  const float A  = fmaf(px, GX, fmaf(py, GY, pz * GZ));
  const float TGA = 2.0f * GAMMA_C * A;
  out[3*i+0] = fmaf(TGA, xi, -LN2_C * WX);
  out[3*i+1] = fmaf(TGA, yi, -LN2_C * WY);
  out[3*i+2] = fmaf(TGA, zi, -LN2_C * WZ);
  out[3*N + 3*i + 0] = GX;
  out[3*N + 3*i + 1] = GY;
  out[3*N + 3*i + 2] = GZ;
}

// ---- Fallback (tiny ws): atomic single-kernel version ----------------------
__global__ __launch_bounds__(TPB) void lddmm_atomic(
    const float* __restrict__ mom, const float* __restrict__ xpt,
    float* __restrict__ out, int N) {
  const int i  = blockIdx.x * TPB + threadIdx.x;
  const int jb = blockIdx.y * TPB;
  __shared__ float4 sA[TPB], sP[TPB];
  {
    const int j = jb + threadIdx.x;
    const float bx = xpt[3*j], by = xpt[3*j+1], bz = xpt[3*j+2];
    sA[threadIdx.x] = make_float4(SB_C*bx, SB_C*by, SB_C*bz,
                                  SC_C * fmaf(bx, bx, fmaf(by, by, bz*bz)));
    sP[threadIdx.x] = make_float4(mom[3*j], mom[3*j+1], mom[3*j+2], 0.f);
  }
  __syncthreads();
  const float xi = xpt[3*i], yi = xpt[3*i+1], zi = xpt[3*i+2];
  const float pxi = mom[3*i], pyi = mom[3*i+1], pzi = mom[3*i+2];
  const float ci = SC_C * fmaf(xi, xi, fmaf(yi, yi, zi*zi));
  float a=0.f, wx=0.f, wy=0.f, wz=0.f, gx=0.f, gy=0.f, gz=0.f;
#pragma unroll 4
  for (int t = 0; t < TPB; ++t) {
    const float4 A = sA[t], P = sP[t];
    const float arg = fmaf(A.x, xi, fmaf(A.y, yi, fmaf(A.z, zi, ci + A.w)));
    const float K   = __builtin_amdgcn_exp2f(arg);
    const float dot = fmaf(P.x, pxi, fmaf(P.y, pyi, P.z * pzi));
    const float w   = K * dot;
    a += w;
    wx = fmaf(w, A.x, wx); wy = fmaf(w, A.y, wy); wz = fmaf(w, A.z, wz);
    gx = fmaf(K, P.x, gx); gy = fmaf(K, P.y, gy); gz = fmaf(K, P.z, gz);
  }
  const float TGA = 2.0f * GAMMA_C * a;
  atomicAdd(&out[3*i+0], fmaf(TGA, xi, -LN2_C * wx));
  atomicAdd(&out[3*i+1], fmaf(TGA, yi, -LN2_C * wy));
  atomicAdd(&out[3*i+2], fmaf(TGA, zi, -LN2_C * wz));
  atomicAdd(&out[3*N+3*i+0], gx);
  atomicAdd(&out[3*N+3*i+1], gy);
  atomicAdd(&out[3*N+3*i+2], gz);
}

extern "C" void kernel_launch(void* const* d_in, const int* in_sizes, int n_in,
                              void* d_out, int out_size, void* d_ws, size_t ws_size,
                              hipStream_t stream) {
  const float* mom = (const float*)d_in[0];   // setup_inputs order: mom first
  const float* xpt = (const float*)d_in[1];   // control_points second
  float* out = (float*)d_out;
  const int N = in_sizes[0] / 3;              // 8192

  // ws layout: part (6*SEG*N floats) | R (6*N floats)
  auto need = [&](int s) { return (size_t)(6*s + 6) * (size_t)N * sizeof(float); };
  int SEG = 128;
  while (SEG > 2 && need(SEG) > ws_size) SEG >>= 1;

  const bool shapes_ok = (N % (TPB * ITILE) == 0) && (N % SEG == 0) &&
                         (N % TPB == 0);
  if (need(SEG) <= ws_size && shapes_ok) {
    const int JT = N / SEG;                   // 64 @ SEG=128
    float* partb = (float*)d_ws;
    float* R     = partb + (size_t)6 * SEG * N;
    const size_t shmem = (size_t)JT * 2 * sizeof(float4);   // 2 KB @ JT=64
    dim3 gA(N / (TPB * ITILE), SEG);          // (16, 128) = 2048 blocks, 8/CU
    lddmm_partial<<<gA, TPB, shmem, stream>>>(mom, xpt, partb, N, SEG, JT);
    dim3 gB(N / TPB, 6);                      // 192 blocks — parallel reduce
    lddmm_reduce<<<gB, TPB, 0, stream>>>(partb, R, N, SEG);
    lddmm_finalize<<<N / TPB, TPB, 0, stream>>>(R, xpt, mom, out, N);
  } else {
    hipMemsetAsync(d_out, 0, (size_t)out_size * sizeof(float), stream);
    dim3 grid(N / TPB, N / TPB);
    lddmm_atomic<<<grid, TPB, 0, stream>>>(mom, xpt, out, N);
  }
}

// Round 8
// 94.944 us; speedup vs baseline: 2.3249x; 1.0735x over previous
//
#include <hip/hip_runtime.h>

// LDDMM variational evolve: B=1, N=8192, D=3, fp32.
// dmom_i = 2g * (x_i * sum_j w_ij  -  sum_j w_ij x_j),  w_ij = K_ij <p_i,p_j>
// dx_i   = sum_j K_ij p_j,   K_ij = exp(-g |x_i - x_j|^2), g = 100.
//
// Round 11: consolidation. Evidence ledger: partial = ~20us j-loop AT the
// issue roofline (44 cyc/pair: 28 fma + 16 exp busy-cycles -- r5 PMC fit)
// + ~20us idle untouched by waves/ILP/instr-count. Only store volume and
// reduce traffic remain adjustable: SEG 128->64 halves part to 12.6MB
// (-2us drain, reduce 5->3us). Shell = r0's proven config (TPB 256,
// lb(256,4), VGPR~40, 4 blocks/CU) + r6's 6-channel A=p_i.G_i trick.
// Ruled out this round: MFMA (no fp32 MFMA; bf16 d^2 error ~40% on K),
// distance culling (gamma=100 cull radius ~0.93 covers the unit cube).
// NOTE: ci must stay inside the exponent (arg <= 0 always); factoring
// exp2(ci) out overflows: inner arg reaches +432 -> inf * 0 = NaN.

#define TPB 256
#define ITILE 2
constexpr float GAMMA_C = 100.0f;
constexpr float LOG2E_C = 1.4426950408889634f;
constexpr float SB_C    = 2.0f * GAMMA_C * LOG2E_C;  // A.xyz = SB*x_j
constexpr float SC_C    = -GAMMA_C * LOG2E_C;        // A.w   = SC*|x_j|^2
constexpr float LN2_C   = 0.69314718055994531f;      // 2g/SB

// ---- Kernel A: per-segment partial sums ------------------------------------
// grid (N/(TPB*ITILE), SEG). part layout: P[c][s][i], c=0..5 (wx,wy,wz,gx,gy,gz).
__global__ __launch_bounds__(TPB, 4) void lddmm_partial(
    const float* __restrict__ mom, const float* __restrict__ xpt,
    float* __restrict__ part, int N, int SEG, int JT) {
  extern __shared__ float4 smem[];
  float4* sA = smem;        // {SB*x, SB*y, SB*z, SC*|x|^2}
  float4* sP = smem + JT;   // {px, py, pz, 0}
  const int tid = threadIdx.x;
  const int seg = blockIdx.y;

  for (int t = tid; t < JT; t += TPB) {
    const int j = seg * JT + t;
    const float bx = xpt[3*j], by = xpt[3*j+1], bz = xpt[3*j+2];
    sA[t] = make_float4(SB_C*bx, SB_C*by, SB_C*bz,
                        SC_C * fmaf(bx, bx, fmaf(by, by, bz*bz)));
    sP[t] = make_float4(mom[3*j], mom[3*j+1], mom[3*j+2], 0.f);
  }
  __syncthreads();

  const int i0 = blockIdx.x * (TPB * ITILE) + tid;
  const int i1 = i0 + TPB;

  const float x0 = xpt[3*i0], y0 = xpt[3*i0+1], z0 = xpt[3*i0+2];
  const float p0x = mom[3*i0], p0y = mom[3*i0+1], p0z = mom[3*i0+2];
  const float c0 = SC_C * fmaf(x0, x0, fmaf(y0, y0, z0*z0));
  const float x1 = xpt[3*i1], y1 = xpt[3*i1+1], z1 = xpt[3*i1+2];
  const float p1x = mom[3*i1], p1y = mom[3*i1+1], p1z = mom[3*i1+2];
  const float c1 = SC_C * fmaf(x1, x1, fmaf(y1, y1, z1*z1));

  float wx0=0.f, wy0=0.f, wz0=0.f, gx0=0.f, gy0=0.f, gz0=0.f;
  float wx1=0.f, wy1=0.f, wz1=0.f, gx1=0.f, gy1=0.f, gz1=0.f;

#pragma unroll 4
  for (int t = 0; t < JT; ++t) {
    const float4 A = sA[t];   // broadcast (same addr all lanes): conflict-free
    const float4 P = sP[t];
    // i0  (14 VALU + 1 exp; row-sum dropped, A_i recovered as p_i.G_i)
    {
      const float arg = fmaf(A.x, x0, fmaf(A.y, y0, fmaf(A.z, z0, c0 + A.w)));
      const float K   = __builtin_amdgcn_exp2f(arg);          // bare v_exp_f32
      const float dot = fmaf(P.x, p0x, fmaf(P.y, p0y, P.z * p0z));
      const float w   = K * dot;
      wx0 = fmaf(w, A.x, wx0); wy0 = fmaf(w, A.y, wy0); wz0 = fmaf(w, A.z, wz0);
      gx0 = fmaf(K, P.x, gx0); gy0 = fmaf(K, P.y, gy0); gz0 = fmaf(K, P.z, gz0);
    }
    // i1
    {
      const float arg = fmaf(A.x, x1, fmaf(A.y, y1, fmaf(A.z, z1, c1 + A.w)));
      const float K   = __builtin_amdgcn_exp2f(arg);
      const float dot = fmaf(P.x, p1x, fmaf(P.y, p1y, P.z * p1z));
      const float w   = K * dot;
      wx1 = fmaf(w, A.x, wx1); wy1 = fmaf(w, A.y, wy1); wz1 = fmaf(w, A.z, wz1);
      gx1 = fmaf(K, P.x, gx1); gy1 = fmaf(K, P.y, gy1); gz1 = fmaf(K, P.z, gz1);
    }
  }

  const size_t SN = (size_t)SEG * N;
  float* p = part + (size_t)seg * N;
  p[0*SN+i0] = wx0; p[0*SN+i1] = wx1;
  p[1*SN+i0] = wy0; p[1*SN+i1] = wy1;
  p[2*SN+i0] = wz0; p[2*SN+i1] = wz1;
  p[3*SN+i0] = gx0; p[3*SN+i1] = gx1;
  p[4*SN+i0] = gy0; p[4*SN+i1] = gy1;
  p[5*SN+i0] = gz0; p[5*SN+i1] = gz1;
}

// ---- Kernel B: reduce over segments (parallel over channels) ---------------
__global__ __launch_bounds__(TPB) void lddmm_reduce(
    const float* __restrict__ part, float* __restrict__ R, int N, int SEG) {
  const int i = blockIdx.x * TPB + threadIdx.x;
  const int c = blockIdx.y;
  const float* src = part + (size_t)c * SEG * N + i;
  float s0 = 0.f, s1 = 0.f, s2 = 0.f, s3 = 0.f;
  int s = 0;
  for (; s + 4 <= SEG; s += 4) {
    s0 += src[(size_t)(s+0)*N]; s1 += src[(size_t)(s+1)*N];
    s2 += src[(size_t)(s+2)*N]; s3 += src[(size_t)(s+3)*N];
  }
  for (; s < SEG; ++s) s0 += src[(size_t)s*N];
  R[(size_t)c * N + i] = (s0 + s1) + (s2 + s3);
}

// ---- Kernel C: finalize ----------------------------------------------------
// A_i = p_i . G_i (row-sum of W, recovered from the reduced G channels).
__global__ __launch_bounds__(TPB) void lddmm_finalize(
    const float* __restrict__ R, const float* __restrict__ xpt,
    const float* __restrict__ mom, float* __restrict__ out, int N) {
  const int i = blockIdx.x * TPB + threadIdx.x;
  const float WX = R[(size_t)0*N+i], WY = R[(size_t)1*N+i], WZ = R[(size_t)2*N+i];
  const float GX = R[(size_t)3*N+i], GY = R[(size_t)4*N+i], GZ = R[(size_t)5*N+i];
  const float xi = xpt[3*i], yi = xpt[3*i+1], zi = xpt[3*i+2];
  const float px = mom[3*i], py = mom[3*i+1], pz = mom[3*i+2];
  const float A  = fmaf(px, GX, fmaf(py, GY, pz * GZ));
  const float TGA = 2.0f * GAMMA_C * A;
  out[3*i+0] = fmaf(TGA, xi, -LN2_C * WX);
  out[3*i+1] = fmaf(TGA, yi, -LN2_C * WY);
  out[3*i+2] = fmaf(TGA, zi, -LN2_C * WZ);
  out[3*N + 3*i + 0] = GX;
  out[3*N + 3*i + 1] = GY;
  out[3*N + 3*i + 2] = GZ;
}

// ---- Fallback (tiny ws): atomic single-kernel version ----------------------
__global__ __launch_bounds__(TPB) void lddmm_atomic(
    const float* __restrict__ mom, const float* __restrict__ xpt,
    float* __restrict__ out, int N) {
  const int i  = blockIdx.x * TPB + threadIdx.x;
  const int jb = blockIdx.y * TPB;
  __shared__ float4 sA[TPB], sP[TPB];
  {
    const int j = jb + threadIdx.x;
    const float bx = xpt[3*j], by = xpt[3*j+1], bz = xpt[3*j+2];
    sA[threadIdx.x] = make_float4(SB_C*bx, SB_C*by, SB_C*bz,
                                  SC_C * fmaf(bx, bx, fmaf(by, by, bz*bz)));
    sP[threadIdx.x] = make_float4(mom[3*j], mom[3*j+1], mom[3*j+2], 0.f);
  }
  __syncthreads();
  const float xi = xpt[3*i], yi = xpt[3*i+1], zi = xpt[3*i+2];
  const float pxi = mom[3*i], pyi = mom[3*i+1], pzi = mom[3*i+2];
  const float ci = SC_C * fmaf(xi, xi, fmaf(yi, yi, zi*zi));
  float a=0.f, wx=0.f, wy=0.f, wz=0.f, gx=0.f, gy=0.f, gz=0.f;
#pragma unroll 4
  for (int t = 0; t < TPB; ++t) {
    const float4 A = sA[t], P = sP[t];
    const float arg = fmaf(A.x, xi, fmaf(A.y, yi, fmaf(A.z, zi, ci + A.w)));
    const float K   = __builtin_amdgcn_exp2f(arg);
    const float dot = fmaf(P.x, pxi, fmaf(P.y, pyi, P.z * pzi));
    const float w   = K * dot;
    a += w;
    wx = fmaf(w, A.x, wx); wy = fmaf(w, A.y, wy); wz = fmaf(w, A.z, wz);
    gx = fmaf(K, P.x, gx); gy = fmaf(K, P.y, gy); gz = fmaf(K, P.z, gz);
  }
  const float TGA = 2.0f * GAMMA_C * a;
  atomicAdd(&out[3*i+0], fmaf(TGA, xi, -LN2_C * wx));
  atomicAdd(&out[3*i+1], fmaf(TGA, yi, -LN2_C * wy));
  atomicAdd(&out[3*i+2], fmaf(TGA, zi, -LN2_C * wz));
  atomicAdd(&out[3*N+3*i+0], gx);
  atomicAdd(&out[3*N+3*i+1], gy);
  atomicAdd(&out[3*N+3*i+2], gz);
}

extern "C" void kernel_launch(void* const* d_in, const int* in_sizes, int n_in,
                              void* d_out, int out_size, void* d_ws, size_t ws_size,
                              hipStream_t stream) {
  const float* mom = (const float*)d_in[0];   // setup_inputs order: mom first
  const float* xpt = (const float*)d_in[1];   // control_points second
  float* out = (float*)d_out;
  const int N = in_sizes[0] / 3;              // 8192

  // ws layout: part (6*SEG*N floats) | R (6*N floats)
  auto need = [&](int s) { return (size_t)(6*s + 6) * (size_t)N * sizeof(float); };
  int SEG = 64;                               // 12.6 MB partials
  while (SEG > 2 && need(SEG) > ws_size) SEG >>= 1;

  const bool shapes_ok = (N % (TPB * ITILE) == 0) && (N % SEG == 0) &&
                         (N % TPB == 0) && ((N / SEG) <= TPB);
  if (need(SEG) <= ws_size && shapes_ok) {
    const int JT = N / SEG;                   // 128 @ SEG=64
    float* partb = (float*)d_ws;
    float* R     = partb + (size_t)6 * SEG * N;
    const size_t shmem = (size_t)JT * 2 * sizeof(float4);   // 4 KB @ JT=128
    dim3 gA(N / (TPB * ITILE), SEG);          // (16, 64) = 1024 blocks, 4/CU
    lddmm_partial<<<gA, TPB, shmem, stream>>>(mom, xpt, partb, N, SEG, JT);
    dim3 gB(N / TPB, 6);                      // 192 blocks — parallel reduce
    lddmm_reduce<<<gB, TPB, 0, stream>>>(partb, R, N, SEG);
    lddmm_finalize<<<N / TPB, TPB, 0, stream>>>(R, xpt, mom, out, N);
  } else {
    hipMemsetAsync(d_out, 0, (size_t)out_size * sizeof(float), stream);
    dim3 grid(N / TPB, N / TPB);
    lddmm_atomic<<<grid, TPB, 0, stream>>>(mom, xpt, out, N);
  }
}